// Round 2
// baseline (618.450 us; speedup 1.0000x reference)
//
#include <hip/hip_runtime.h>

typedef unsigned int u32;
typedef unsigned short u16;
typedef __attribute__((ext_vector_type(8))) short short8;
typedef __attribute__((ext_vector_type(4))) float f32x4;

#define D_IN 128
#define D_HID 128
#define D_OUT 16

__device__ inline u16 rne_bf16(float f) {
    u32 x = __float_as_uint(f);
    u32 r = x + 0x7fffu + ((x >> 16) & 1u);
    return (u16)(r >> 16);
}
__device__ inline float bu2f(u16 u) { return __uint_as_float(((u32)u) << 16); }

// ---------------- preprocessing ----------------

// flag: 1 if edge_index is int32 layout, 0 if int64 (odd words all zero).
__global__ __launch_bounds__(256) void detect_k(const int* __restrict__ ei,
                                                u32* __restrict__ flag, int n) {
    int i = blockIdx.x * 256 + threadIdx.x;
    if (i < n && (i & 1) && ei[i] != 0) atomicOr(flag, 1u);
}

__device__ inline int load_row(const int* ei, u32 f, int e, int E) {
    int v = f ? ei[e] : ei[2 * e];
    return v;
}
__device__ inline int load_col(const int* ei, u32 f, int e, int E) {
    int v = f ? ei[E + e] : ei[2 * E + 2 * e];
    return v;
}
__device__ inline int clampi(int v, int n) {
    v = v < 0 ? 0 : v;
    return v >= n ? n - 1 : v;
}

__global__ __launch_bounds__(256) void count_rows(const int* __restrict__ ei,
                                                  const u32* __restrict__ flag,
                                                  u32* __restrict__ cnt, int E, int N) {
    int e = blockIdx.x * 256 + threadIdx.x;
    if (e >= E) return;
    u32 f = *flag;
    int r = clampi(load_row(ei, f, e, E), N);
    atomicAdd(&cnt[r], 1u);
}

__global__ __launch_bounds__(256) void dinv_k(const u32* __restrict__ cnt,
                                              float* __restrict__ dinv, int n) {
    int i = blockIdx.x * 256 + threadIdx.x;
    if (i < n) dinv[i] = rsqrtf((float)(cnt[i] + 1u));  // +1 self loop
}

__global__ __launch_bounds__(256) void scan1(const u32* __restrict__ cnt,
                                             u32* __restrict__ excl,
                                             u32* __restrict__ partial, int n) {
    __shared__ u32 sm[256];
    int tid = threadIdx.x;
    int i = blockIdx.x * 256 + tid;
    u32 v = (i < n) ? cnt[i] : 0u;
    sm[tid] = v;
    __syncthreads();
    for (int off = 1; off < 256; off <<= 1) {
        u32 t = (tid >= off) ? sm[tid - off] : 0u;
        __syncthreads();
        sm[tid] += t;
        __syncthreads();
    }
    if (i < n) excl[i] = sm[tid] - v;
    if (tid == 255) partial[blockIdx.x] = sm[255];
}

__global__ __launch_bounds__(512) void scan2(u32* __restrict__ partial, int nb) {
    __shared__ u32 sm[512];
    int tid = threadIdx.x;
    u32 v = (tid < nb) ? partial[tid] : 0u;
    sm[tid] = v;
    __syncthreads();
    for (int off = 1; off < 512; off <<= 1) {
        u32 t = (tid >= off) ? sm[tid - off] : 0u;
        __syncthreads();
        sm[tid] += t;
        __syncthreads();
    }
    if (tid < nb) partial[tid] = sm[tid] - v;
}

__global__ __launch_bounds__(256) void scan3(u32* __restrict__ excl,
                                             const u32* __restrict__ partial,
                                             int n, int E) {
    int i = blockIdx.x * 256 + threadIdx.x;
    if (i < n) excl[i] += partial[blockIdx.x];
    if (i == 0) excl[n] = (u32)E;
}

__global__ __launch_bounds__(256) void scatter_k(const int* __restrict__ ei,
                                                 const u32* __restrict__ flag,
                                                 const float* __restrict__ dinv,
                                                 const u32* __restrict__ row_start,
                                                 u32* __restrict__ cursor,
                                                 uint2* __restrict__ edata, int E, int N) {
    int e = blockIdx.x * 256 + threadIdx.x;
    if (e >= E) return;
    u32 f = *flag;
    int r = clampi(load_row(ei, f, e, E), N);
    int c = clampi(load_col(ei, f, e, E), N);
    u32 pos = row_start[r] + atomicAdd(&cursor[r], 1u);
    if (pos < (u32)E)
        edata[pos] = make_uint2((u32)c, __float_as_uint(dinv[r] * dinv[c]));
}

// Split fp32 W [128 x (ntiles*16)] into hi/lo bf16 MFMA B-fragments.
// frag (s,t): lane holds W[s*32 + (lane>>4)*8 + j][t*16 + (lane&15)], j=0..7
__global__ __launch_bounds__(256) void reformat_w(const float* __restrict__ W,
                                                  u16* __restrict__ Wh,
                                                  u16* __restrict__ Wl, int ntiles) {
    int idx = blockIdx.x * 256 + threadIdx.x;
    int total = 4 * ntiles * 64;
    if (idx >= total) return;
    int lane = idx & 63;
    int st = idx >> 6;
    int t = st % ntiles;
    int s = st / ntiles;
    int Nc = ntiles * 16;
    int n = t * 16 + (lane & 15);
    int kb = lane >> 4;
    short8 vh, vl;
#pragma unroll
    for (int j = 0; j < 8; j++) {
        float w = W[(size_t)(s * 32 + kb * 8 + j) * Nc + n];
        u16 hi = rne_bf16(w);
        u16 lo = rne_bf16(w - bu2f(hi));
        vh[j] = (short)hi;
        vl[j] = (short)lo;
    }
    *(short8*)(Wh + (size_t)idx * 8) = vh;
    *(short8*)(Wl + (size_t)idx * 8) = vl;
}

// ---------------- GEMM (split-bf16 MFMA 16x16x32, fp32-accurate) ----------------
// A [M x 128] fp32 row-major; Wh/Wl pre-swizzled; H [M x Ncols] fp32.
__global__ __launch_bounds__(256) void gemm128(const float* __restrict__ A,
                                               const u16* __restrict__ Wh,
                                               const u16* __restrict__ Wl,
                                               float* __restrict__ H, int M) {
    int wave = threadIdx.x >> 6, lane = threadIdx.x & 63;
    int mbase = blockIdx.x * 64 + wave * 16;
    int mload = mbase + (lane & 15);
    if (mload >= M) mload = M - 1;
    int kq = lane >> 4;
    f32x4 acc[8];
#pragma unroll
    for (int t = 0; t < 8; t++) acc[t] = (f32x4){0.f, 0.f, 0.f, 0.f};
#pragma unroll
    for (int s = 0; s < 4; s++) {
        const float* ap = A + (size_t)mload * 128 + s * 32 + kq * 8;
        short8 ah, al;
#pragma unroll
        for (int j = 0; j < 8; j++) {
            float v = ap[j];
            u16 hi = rne_bf16(v);
            u16 lo = rne_bf16(v - bu2f(hi));
            ah[j] = (short)hi;
            al[j] = (short)lo;
        }
#pragma unroll
        for (int t = 0; t < 8; t++) {
            short8 bh = *(const short8*)(Wh + (size_t)((s * 8 + t) * 64 + lane) * 8);
            short8 bl = *(const short8*)(Wl + (size_t)((s * 8 + t) * 64 + lane) * 8);
            acc[t] = __builtin_amdgcn_mfma_f32_16x16x32_bf16(ah, bh, acc[t], 0, 0, 0);
            acc[t] = __builtin_amdgcn_mfma_f32_16x16x32_bf16(ah, bl, acc[t], 0, 0, 0);
            acc[t] = __builtin_amdgcn_mfma_f32_16x16x32_bf16(al, bh, acc[t], 0, 0, 0);
        }
    }
    int coln = lane & 15;
    int rbase = mbase + ((lane >> 4) << 2);
#pragma unroll
    for (int t = 0; t < 8; t++) {
#pragma unroll
        for (int i = 0; i < 4; i++) {
            int rr = rbase + i;
            if (rr < M) H[(size_t)rr * 128 + t * 16 + coln] = acc[t][i];
        }
    }
}

__global__ __launch_bounds__(256) void gemm16(const float* __restrict__ A,
                                              const u16* __restrict__ Wh,
                                              const u16* __restrict__ Wl,
                                              float* __restrict__ H, int M) {
    int wave = threadIdx.x >> 6, lane = threadIdx.x & 63;
    int mbase = blockIdx.x * 64 + wave * 16;
    int mload = mbase + (lane & 15);
    if (mload >= M) mload = M - 1;
    int kq = lane >> 4;
    f32x4 acc = (f32x4){0.f, 0.f, 0.f, 0.f};
#pragma unroll
    for (int s = 0; s < 4; s++) {
        const float* ap = A + (size_t)mload * 128 + s * 32 + kq * 8;
        short8 ah, al;
#pragma unroll
        for (int j = 0; j < 8; j++) {
            float v = ap[j];
            u16 hi = rne_bf16(v);
            u16 lo = rne_bf16(v - bu2f(hi));
            ah[j] = (short)hi;
            al[j] = (short)lo;
        }
        short8 bh = *(const short8*)(Wh + (size_t)(s * 64 + lane) * 8);
        short8 bl = *(const short8*)(Wl + (size_t)(s * 64 + lane) * 8);
        acc = __builtin_amdgcn_mfma_f32_16x16x32_bf16(ah, bh, acc, 0, 0, 0);
        acc = __builtin_amdgcn_mfma_f32_16x16x32_bf16(ah, bl, acc, 0, 0, 0);
        acc = __builtin_amdgcn_mfma_f32_16x16x32_bf16(al, bh, acc, 0, 0, 0);
    }
    int coln = lane & 15;
    int rbase = mbase + ((lane >> 4) << 2);
#pragma unroll
    for (int i = 0; i < 4; i++) {
        int rr = rbase + i;
        if (rr < M) H[(size_t)rr * 16 + coln] = acc[i];
    }
}

// ---------------- aggregation (fp32) ----------------
// One wave per row; lane handles cols 2*lane, 2*lane+1 (float2).
__global__ __launch_bounds__(256) void agg128(const float* __restrict__ h,
                                              const uint2* __restrict__ edata,
                                              const u32* __restrict__ row_start,
                                              const float* __restrict__ dinv,
                                              const float* __restrict__ bias,
                                              float* __restrict__ out, int M,
                                              int do_relu) {
    int wave = threadIdx.x >> 6, lane = threadIdx.x & 63;
    int r = blockIdx.x * 4 + wave;
    if (r >= M) return;
    u32 beg = row_start[r], end = row_start[r + 1];
    const float2* hp = (const float2*)h;
    float ax0 = 0, ay0 = 0, ax1 = 0, ay1 = 0, ax2 = 0, ay2 = 0, ax3 = 0, ay3 = 0;
    u32 e = beg;
    for (; e + 4 <= end; e += 4) {
        uint2 p0 = edata[e], p1 = edata[e + 1], p2 = edata[e + 2], p3 = edata[e + 3];
        float2 v0 = hp[(size_t)p0.x * 64 + lane];
        float2 v1 = hp[(size_t)p1.x * 64 + lane];
        float2 v2 = hp[(size_t)p2.x * 64 + lane];
        float2 v3 = hp[(size_t)p3.x * 64 + lane];
        float n0 = __uint_as_float(p0.y), n1 = __uint_as_float(p1.y);
        float n2 = __uint_as_float(p2.y), n3 = __uint_as_float(p3.y);
        ax0 = fmaf(n0, v0.x, ax0); ay0 = fmaf(n0, v0.y, ay0);
        ax1 = fmaf(n1, v1.x, ax1); ay1 = fmaf(n1, v1.y, ay1);
        ax2 = fmaf(n2, v2.x, ax2); ay2 = fmaf(n2, v2.y, ay2);
        ax3 = fmaf(n3, v3.x, ax3); ay3 = fmaf(n3, v3.y, ay3);
    }
    for (; e < end; ++e) {
        uint2 p = edata[e];
        float2 v = hp[(size_t)p.x * 64 + lane];
        float nn = __uint_as_float(p.y);
        ax0 = fmaf(nn, v.x, ax0);
        ay0 = fmaf(nn, v.y, ay0);
    }
    float dr = dinv[r];
    float sw = dr * dr;
    float2 hs = hp[(size_t)r * 64 + lane];
    float2 bb = ((const float2*)bias)[lane];
    float ax = (ax0 + ax1) + (ax2 + ax3) + sw * hs.x + bb.x;
    float ay = (ay0 + ay1) + (ay2 + ay3) + sw * hs.y + bb.y;
    if (do_relu) {
        ax = fmaxf(ax, 0.f);
        ay = fmaxf(ay, 0.f);
    }
    float2 o;
    o.x = ax;
    o.y = ay;
    ((float2*)out)[(size_t)r * 64 + lane] = o;
}

// 16 lanes per row; fused self-loop + bias + log_softmax; fp32 output.
__global__ __launch_bounds__(256) void agg16_lsm(const float* __restrict__ h3,
                                                 const uint2* __restrict__ edata,
                                                 const u32* __restrict__ row_start,
                                                 const float* __restrict__ dinv,
                                                 const float* __restrict__ bias,
                                                 float* __restrict__ out, int M) {
    int g = threadIdx.x >> 4, l = threadIdx.x & 15;
    int r = blockIdx.x * 16 + g;
    if (r >= M) return;
    u32 beg = row_start[r], end = row_start[r + 1];
    float a0 = 0.f, a1 = 0.f;
    u32 e = beg;
    for (; e + 2 <= end; e += 2) {
        uint2 p0 = edata[e], p1 = edata[e + 1];
        a0 = fmaf(__uint_as_float(p0.y), h3[(size_t)p0.x * 16 + l], a0);
        a1 = fmaf(__uint_as_float(p1.y), h3[(size_t)p1.x * 16 + l], a1);
    }
    if (e < end) {
        uint2 p = edata[e];
        a0 = fmaf(__uint_as_float(p.y), h3[(size_t)p.x * 16 + l], a0);
    }
    float dr = dinv[r];
    float acc = a0 + a1 + dr * dr * h3[(size_t)r * 16 + l] + bias[l];
    float m = acc;
#pragma unroll
    for (int o = 8; o >= 1; o >>= 1) m = fmaxf(m, __shfl_xor(m, o, 16));
    float ex = expf(acc - m);
    float s = ex;
#pragma unroll
    for (int o = 8; o >= 1; o >>= 1) s += __shfl_xor(s, o, 16);
    out[(size_t)r * 16 + l] = acc - m - logf(s);
}

// ---------------- launch ----------------

extern "C" void kernel_launch(void* const* d_in, const int* in_sizes, int n_in,
                              void* d_out, int out_size, void* d_ws, size_t ws_size,
                              hipStream_t stream) {
    const float* x = (const float*)d_in[0];
    const int* ei = (const int*)d_in[1];
    const float* W1 = (const float*)d_in[2];
    const float* b1 = (const float*)d_in[3];
    const float* W2 = (const float*)d_in[4];
    const float* b2 = (const float*)d_in[5];
    const float* W3 = (const float*)d_in[6];
    const float* b3 = (const float*)d_in[7];
    int N = in_sizes[0] / D_IN;
    int E = in_sizes[1] / 2;

    char* p = (char*)d_ws;
    auto alloc = [&](size_t bytes) -> void* {
        void* q = (void*)p;
        p += (bytes + 255) & ~(size_t)255;
        return q;
    };
    u32* cnt = (u32*)alloc((size_t)N * 4);
    u32* cursor = (u32*)alloc((size_t)N * 4);
    float* dinv = (float*)alloc((size_t)N * 4);
    u32* row_start = (u32*)alloc((size_t)(N + 1) * 4);
    u32* partial = (u32*)alloc(4096);
    u32* flag = (u32*)alloc(256);
    uint2* edata = (uint2*)alloc((size_t)E * 8);
    u16* wf1h = (u16*)alloc(16384 * 2);
    u16* wf1l = (u16*)alloc(16384 * 2);
    u16* wf2h = (u16*)alloc(16384 * 2);
    u16* wf2l = (u16*)alloc(16384 * 2);
    u16* wf3h = (u16*)alloc(2048 * 2);
    u16* wf3l = (u16*)alloc(2048 * 2);
    float* h = (float*)alloc((size_t)N * 128 * 4);
    float* act = (float*)alloc((size_t)N * 128 * 4);
    float* h3 = (float*)alloc((size_t)N * 16 * 4);
    (void)ws_size; (void)n_in; (void)out_size;

    hipMemsetAsync(cnt, 0, (size_t)N * 4, stream);
    hipMemsetAsync(cursor, 0, (size_t)N * 4, stream);
    hipMemsetAsync(flag, 0, 4, stream);
    hipMemsetAsync(edata, 0, (size_t)E * 8, stream);

    int eb = (E + 255) / 256;
    int nb = (N + 255) / 256;  // 391 <= 512, scan2 single block handles it
    detect_k<<<32, 256, 0, stream>>>(ei, flag, 8192);
    count_rows<<<eb, 256, 0, stream>>>(ei, flag, cnt, E, N);
    dinv_k<<<nb, 256, 0, stream>>>(cnt, dinv, N);
    scan1<<<nb, 256, 0, stream>>>(cnt, row_start, partial, N);
    scan2<<<1, 512, 0, stream>>>(partial, nb);
    scan3<<<nb, 256, 0, stream>>>(row_start, partial, N, E);
    scatter_k<<<eb, 256, 0, stream>>>(ei, flag, dinv, row_start, cursor, edata, E, N);

    reformat_w<<<8, 256, 0, stream>>>(W1, wf1h, wf1l, 8);
    reformat_w<<<8, 256, 0, stream>>>(W2, wf2h, wf2l, 8);
    reformat_w<<<1, 256, 0, stream>>>(W3, wf3h, wf3l, 1);

    int gb = (N + 63) / 64;
    gemm128<<<gb, 256, 0, stream>>>(x, wf1h, wf1l, h, N);
    agg128<<<(N + 3) / 4, 256, 0, stream>>>(h, edata, row_start, dinv, b1, act, N, 1);
    gemm128<<<gb, 256, 0, stream>>>(act, wf2h, wf2l, h, N);
    agg128<<<(N + 3) / 4, 256, 0, stream>>>(h, edata, row_start, dinv, b2, act, N, 1);
    gemm16<<<gb, 256, 0, stream>>>(act, wf3h, wf3l, h3, N);
    agg16_lsm<<<(N + 15) / 16, 256, 0, stream>>>(h3, edata, row_start, dinv, b3,
                                                 (float*)d_out, N);
}

// Round 3
// 490.580 us; speedup vs baseline: 1.2606x; 1.2606x over previous
//
#include <hip/hip_runtime.h>

typedef unsigned int u32;
typedef unsigned short u16;
typedef _Float16 f16;
typedef __attribute__((ext_vector_type(8))) _Float16 half8;
typedef __attribute__((ext_vector_type(2))) _Float16 half2_t;
typedef __attribute__((ext_vector_type(4))) float f32x4;

#define D_IN 128
#define D_HID 128
#define D_OUT 16

// ---------------- preprocessing ----------------

// flag: 1 if edge_index is int32 layout, 0 if int64 (odd words all zero).
__global__ __launch_bounds__(256) void detect_k(const int* __restrict__ ei,
                                                u32* __restrict__ flag, int n) {
    int i = blockIdx.x * 256 + threadIdx.x;
    if (i < n && (i & 1) && ei[i] != 0) atomicOr(flag, 1u);
}

__device__ inline int load_row(const int* ei, u32 f, int e, int E) {
    return f ? ei[e] : ei[2 * e];
}
__device__ inline int load_col(const int* ei, u32 f, int e, int E) {
    return f ? ei[E + e] : ei[2 * E + 2 * e];
}
__device__ inline int clampi(int v, int n) {
    v = v < 0 ? 0 : v;
    return v >= n ? n - 1 : v;
}

__global__ __launch_bounds__(256) void count_rows(const int* __restrict__ ei,
                                                  const u32* __restrict__ flag,
                                                  u32* __restrict__ cnt, int E, int N) {
    int e = blockIdx.x * 256 + threadIdx.x;
    if (e >= E) return;
    u32 f = *flag;
    int r = clampi(load_row(ei, f, e, E), N);
    atomicAdd(&cnt[r], 1u);
}

__global__ __launch_bounds__(256) void dinv_k(const u32* __restrict__ cnt,
                                              float* __restrict__ dinv, int n) {
    int i = blockIdx.x * 256 + threadIdx.x;
    if (i < n) dinv[i] = rsqrtf((float)(cnt[i] + 1u));  // +1 self loop
}

__global__ __launch_bounds__(256) void scan1(const u32* __restrict__ cnt,
                                             u32* __restrict__ excl,
                                             u32* __restrict__ partial, int n) {
    __shared__ u32 sm[256];
    int tid = threadIdx.x;
    int i = blockIdx.x * 256 + tid;
    u32 v = (i < n) ? cnt[i] : 0u;
    sm[tid] = v;
    __syncthreads();
    for (int off = 1; off < 256; off <<= 1) {
        u32 t = (tid >= off) ? sm[tid - off] : 0u;
        __syncthreads();
        sm[tid] += t;
        __syncthreads();
    }
    if (i < n) excl[i] = sm[tid] - v;
    if (tid == 255) partial[blockIdx.x] = sm[255];
}

__global__ __launch_bounds__(512) void scan2(u32* __restrict__ partial, int nb) {
    __shared__ u32 sm[512];
    int tid = threadIdx.x;
    u32 v = (tid < nb) ? partial[tid] : 0u;
    sm[tid] = v;
    __syncthreads();
    for (int off = 1; off < 512; off <<= 1) {
        u32 t = (tid >= off) ? sm[tid - off] : 0u;
        __syncthreads();
        sm[tid] += t;
        __syncthreads();
    }
    if (tid < nb) partial[tid] = sm[tid] - v;
}

__global__ __launch_bounds__(256) void scan3(u32* __restrict__ excl,
                                             const u32* __restrict__ partial,
                                             int n, int E) {
    int i = blockIdx.x * 256 + threadIdx.x;
    if (i < n) excl[i] += partial[blockIdx.x];
    if (i == 0) excl[n] = (u32)E;
}

__global__ __launch_bounds__(256) void scatter_k(const int* __restrict__ ei,
                                                 const u32* __restrict__ flag,
                                                 const float* __restrict__ dinv,
                                                 const u32* __restrict__ row_start,
                                                 u32* __restrict__ cursor,
                                                 uint2* __restrict__ edata, int E, int N) {
    int e = blockIdx.x * 256 + threadIdx.x;
    if (e >= E) return;
    u32 f = *flag;
    int r = clampi(load_row(ei, f, e, E), N);
    int c = clampi(load_col(ei, f, e, E), N);
    u32 pos = row_start[r] + atomicAdd(&cursor[r], 1u);
    if (pos < (u32)E)
        edata[pos] = make_uint2((u32)c, __float_as_uint(dinv[r] * dinv[c]));
}

// Split fp32 W [128 x (ntiles*16)] into hi/lo f16 MFMA B-fragments.
// frag (s,t): lane holds W[s*32 + (lane>>4)*8 + j][t*16 + (lane&15)], j=0..7
__global__ __launch_bounds__(256) void reformat_w(const float* __restrict__ W,
                                                  f16* __restrict__ Wh,
                                                  f16* __restrict__ Wl, int ntiles) {
    int idx = blockIdx.x * 256 + threadIdx.x;
    int total = 4 * ntiles * 64;
    if (idx >= total) return;
    int lane = idx & 63;
    int st = idx >> 6;
    int t = st % ntiles;
    int s = st / ntiles;
    int Nc = ntiles * 16;
    int n = t * 16 + (lane & 15);
    int kb = lane >> 4;
    half8 vh, vl;
#pragma unroll
    for (int j = 0; j < 8; j++) {
        float w = W[(size_t)(s * 32 + kb * 8 + j) * Nc + n];
        f16 hi = (f16)w;
        f16 lo = (f16)(w - (float)hi);
        vh[j] = hi;
        vl[j] = lo;
    }
    *(half8*)(Wh + (size_t)idx * 8) = vh;
    *(half8*)(Wl + (size_t)idx * 8) = vl;
}

// ---------------- GEMMs (f16 MFMA 16x16x32, fp32-accurate via splits) --------

// Layer 1: A fp32 [M x 128]; split A into f16 hi/lo; 3 MFMAs; H out f16.
__global__ __launch_bounds__(256) void gemm128_l1(const float* __restrict__ A,
                                                  const f16* __restrict__ Wh,
                                                  const f16* __restrict__ Wl,
                                                  f16* __restrict__ H, int M) {
    int wave = threadIdx.x >> 6, lane = threadIdx.x & 63;
    int mbase = blockIdx.x * 64 + wave * 16;
    int mload = mbase + (lane & 15);
    if (mload >= M) mload = M - 1;
    int kq = lane >> 4;
    f32x4 acc[8];
#pragma unroll
    for (int t = 0; t < 8; t++) acc[t] = (f32x4){0.f, 0.f, 0.f, 0.f};
#pragma unroll
    for (int s = 0; s < 4; s++) {
        const float* ap = A + (size_t)mload * 128 + s * 32 + kq * 8;
        half8 ah, al;
#pragma unroll
        for (int j = 0; j < 8; j++) {
            float v = ap[j];
            f16 hi = (f16)v;
            ah[j] = hi;
            al[j] = (f16)(v - (float)hi);
        }
#pragma unroll
        for (int t = 0; t < 8; t++) {
            half8 bh = *(const half8*)(Wh + (size_t)((s * 8 + t) * 64 + lane) * 8);
            half8 bl = *(const half8*)(Wl + (size_t)((s * 8 + t) * 64 + lane) * 8);
            acc[t] = __builtin_amdgcn_mfma_f32_16x16x32_f16(ah, bh, acc[t], 0, 0, 0);
            acc[t] = __builtin_amdgcn_mfma_f32_16x16x32_f16(ah, bl, acc[t], 0, 0, 0);
            acc[t] = __builtin_amdgcn_mfma_f32_16x16x32_f16(al, bh, acc[t], 0, 0, 0);
        }
    }
    int coln = lane & 15;
    int rbase = mbase + ((lane >> 4) << 2);
#pragma unroll
    for (int t = 0; t < 8; t++) {
#pragma unroll
        for (int i = 0; i < 4; i++) {
            int rr = rbase + i;
            if (rr < M) H[(size_t)rr * 128 + t * 16 + coln] = (f16)acc[t][i];
        }
    }
}

// Layers 2: A f16 exact [M x 128]; 2 MFMAs (A*Wh + A*Wl); H out f16.
__global__ __launch_bounds__(256) void gemm128_l2(const f16* __restrict__ A,
                                                  const f16* __restrict__ Wh,
                                                  const f16* __restrict__ Wl,
                                                  f16* __restrict__ H, int M) {
    int wave = threadIdx.x >> 6, lane = threadIdx.x & 63;
    int mbase = blockIdx.x * 64 + wave * 16;
    int mload = mbase + (lane & 15);
    if (mload >= M) mload = M - 1;
    int kq = lane >> 4;
    f32x4 acc[8];
#pragma unroll
    for (int t = 0; t < 8; t++) acc[t] = (f32x4){0.f, 0.f, 0.f, 0.f};
#pragma unroll
    for (int s = 0; s < 4; s++) {
        half8 a = *(const half8*)(A + (size_t)mload * 128 + s * 32 + kq * 8);
#pragma unroll
        for (int t = 0; t < 8; t++) {
            half8 bh = *(const half8*)(Wh + (size_t)((s * 8 + t) * 64 + lane) * 8);
            half8 bl = *(const half8*)(Wl + (size_t)((s * 8 + t) * 64 + lane) * 8);
            acc[t] = __builtin_amdgcn_mfma_f32_16x16x32_f16(a, bh, acc[t], 0, 0, 0);
            acc[t] = __builtin_amdgcn_mfma_f32_16x16x32_f16(a, bl, acc[t], 0, 0, 0);
        }
    }
    int coln = lane & 15;
    int rbase = mbase + ((lane >> 4) << 2);
#pragma unroll
    for (int t = 0; t < 8; t++) {
#pragma unroll
        for (int i = 0; i < 4; i++) {
            int rr = rbase + i;
            if (rr < M) H[(size_t)rr * 128 + t * 16 + coln] = (f16)acc[t][i];
        }
    }
}

// Layer 3: A f16 [M x 128] -> H3 f16 [M x 16]; 2 MFMAs per s.
__global__ __launch_bounds__(256) void gemm16(const f16* __restrict__ A,
                                              const f16* __restrict__ Wh,
                                              const f16* __restrict__ Wl,
                                              f16* __restrict__ H, int M) {
    int wave = threadIdx.x >> 6, lane = threadIdx.x & 63;
    int mbase = blockIdx.x * 64 + wave * 16;
    int mload = mbase + (lane & 15);
    if (mload >= M) mload = M - 1;
    int kq = lane >> 4;
    f32x4 acc = (f32x4){0.f, 0.f, 0.f, 0.f};
#pragma unroll
    for (int s = 0; s < 4; s++) {
        half8 a = *(const half8*)(A + (size_t)mload * 128 + s * 32 + kq * 8);
        half8 bh = *(const half8*)(Wh + (size_t)(s * 64 + lane) * 8);
        half8 bl = *(const half8*)(Wl + (size_t)(s * 64 + lane) * 8);
        acc = __builtin_amdgcn_mfma_f32_16x16x32_f16(a, bh, acc, 0, 0, 0);
        acc = __builtin_amdgcn_mfma_f32_16x16x32_f16(a, bl, acc, 0, 0, 0);
    }
    int coln = lane & 15;
    int rbase = mbase + ((lane >> 4) << 2);
#pragma unroll
    for (int i = 0; i < 4; i++) {
        int rr = rbase + i;
        if (rr < M) H[(size_t)rr * 16 + coln] = (f16)acc[i];
    }
}

// ---------------- aggregation ----------------
// One wave per row; lane handles features 2*lane, 2*lane+1 (half2 = 4B/lane).
// fp32 accumulate; unroll 8 for memory-level parallelism.
__global__ __launch_bounds__(256) void agg128(const f16* __restrict__ h,
                                              const uint2* __restrict__ edata,
                                              const u32* __restrict__ row_start,
                                              const float* __restrict__ dinv,
                                              const float* __restrict__ bias,
                                              f16* __restrict__ out, int M,
                                              int do_relu) {
    int wave = threadIdx.x >> 6, lane = threadIdx.x & 63;
    int r = blockIdx.x * 4 + wave;
    if (r >= M) return;
    u32 beg = row_start[r], end = row_start[r + 1];
    const half2_t* hp = (const half2_t*)h;
    float ax0 = 0, ay0 = 0, ax1 = 0, ay1 = 0, ax2 = 0, ay2 = 0, ax3 = 0, ay3 = 0;
    u32 e = beg;
    for (; e + 8 <= end; e += 8) {
        uint2 p0 = edata[e],     p1 = edata[e + 1], p2 = edata[e + 2], p3 = edata[e + 3];
        uint2 p4 = edata[e + 4], p5 = edata[e + 5], p6 = edata[e + 6], p7 = edata[e + 7];
        half2_t v0 = hp[(size_t)p0.x * 64 + lane];
        half2_t v1 = hp[(size_t)p1.x * 64 + lane];
        half2_t v2 = hp[(size_t)p2.x * 64 + lane];
        half2_t v3 = hp[(size_t)p3.x * 64 + lane];
        half2_t v4 = hp[(size_t)p4.x * 64 + lane];
        half2_t v5 = hp[(size_t)p5.x * 64 + lane];
        half2_t v6 = hp[(size_t)p6.x * 64 + lane];
        half2_t v7 = hp[(size_t)p7.x * 64 + lane];
        float n0 = __uint_as_float(p0.y), n1 = __uint_as_float(p1.y);
        float n2 = __uint_as_float(p2.y), n3 = __uint_as_float(p3.y);
        float n4 = __uint_as_float(p4.y), n5 = __uint_as_float(p5.y);
        float n6 = __uint_as_float(p6.y), n7 = __uint_as_float(p7.y);
        ax0 = fmaf(n0, (float)v0[0], ax0); ay0 = fmaf(n0, (float)v0[1], ay0);
        ax1 = fmaf(n1, (float)v1[0], ax1); ay1 = fmaf(n1, (float)v1[1], ay1);
        ax2 = fmaf(n2, (float)v2[0], ax2); ay2 = fmaf(n2, (float)v2[1], ay2);
        ax3 = fmaf(n3, (float)v3[0], ax3); ay3 = fmaf(n3, (float)v3[1], ay3);
        ax0 = fmaf(n4, (float)v4[0], ax0); ay0 = fmaf(n4, (float)v4[1], ay0);
        ax1 = fmaf(n5, (float)v5[0], ax1); ay1 = fmaf(n5, (float)v5[1], ay1);
        ax2 = fmaf(n6, (float)v6[0], ax2); ay2 = fmaf(n6, (float)v6[1], ay2);
        ax3 = fmaf(n7, (float)v7[0], ax3); ay3 = fmaf(n7, (float)v7[1], ay3);
    }
    for (; e + 2 <= end; e += 2) {
        uint2 p0 = edata[e], p1 = edata[e + 1];
        half2_t v0 = hp[(size_t)p0.x * 64 + lane];
        half2_t v1 = hp[(size_t)p1.x * 64 + lane];
        float n0 = __uint_as_float(p0.y), n1 = __uint_as_float(p1.y);
        ax0 = fmaf(n0, (float)v0[0], ax0); ay0 = fmaf(n0, (float)v0[1], ay0);
        ax1 = fmaf(n1, (float)v1[0], ax1); ay1 = fmaf(n1, (float)v1[1], ay1);
    }
    if (e < end) {
        uint2 p = edata[e];
        half2_t v = hp[(size_t)p.x * 64 + lane];
        float nn = __uint_as_float(p.y);
        ax0 = fmaf(nn, (float)v[0], ax0);
        ay0 = fmaf(nn, (float)v[1], ay0);
    }
    float dr = dinv[r];
    float sw = dr * dr;
    half2_t hs = hp[(size_t)r * 64 + lane];
    float2 bb = ((const float2*)bias)[lane];
    float ax = (ax0 + ax1) + (ax2 + ax3) + sw * (float)hs[0] + bb.x;
    float ay = (ay0 + ay1) + (ay2 + ay3) + sw * (float)hs[1] + bb.y;
    if (do_relu) {
        ax = fmaxf(ax, 0.f);
        ay = fmaxf(ay, 0.f);
    }
    half2_t o;
    o[0] = (f16)ax;
    o[1] = (f16)ay;
    ((half2_t*)out)[(size_t)r * 64 + lane] = o;
}

// 16 lanes per row; fused self-loop + bias + log_softmax; fp32 output.
__global__ __launch_bounds__(256) void agg16_lsm(const f16* __restrict__ h3,
                                                 const uint2* __restrict__ edata,
                                                 const u32* __restrict__ row_start,
                                                 const float* __restrict__ dinv,
                                                 const float* __restrict__ bias,
                                                 float* __restrict__ out, int M) {
    int g = threadIdx.x >> 4, l = threadIdx.x & 15;
    int r = blockIdx.x * 16 + g;
    if (r >= M) return;
    u32 beg = row_start[r], end = row_start[r + 1];
    float a0 = 0.f, a1 = 0.f, a2 = 0.f, a3 = 0.f;
    u32 e = beg;
    for (; e + 4 <= end; e += 4) {
        uint2 p0 = edata[e], p1 = edata[e + 1], p2 = edata[e + 2], p3 = edata[e + 3];
        a0 = fmaf(__uint_as_float(p0.y), (float)h3[(size_t)p0.x * 16 + l], a0);
        a1 = fmaf(__uint_as_float(p1.y), (float)h3[(size_t)p1.x * 16 + l], a1);
        a2 = fmaf(__uint_as_float(p2.y), (float)h3[(size_t)p2.x * 16 + l], a2);
        a3 = fmaf(__uint_as_float(p3.y), (float)h3[(size_t)p3.x * 16 + l], a3);
    }
    for (; e < end; ++e) {
        uint2 p = edata[e];
        a0 = fmaf(__uint_as_float(p.y), (float)h3[(size_t)p.x * 16 + l], a0);
    }
    float dr = dinv[r];
    float acc = (a0 + a1) + (a2 + a3) + dr * dr * (float)h3[(size_t)r * 16 + l] +
                bias[l];
    float m = acc;
#pragma unroll
    for (int o = 8; o >= 1; o >>= 1) m = fmaxf(m, __shfl_xor(m, o, 16));
    float ex = expf(acc - m);
    float s = ex;
#pragma unroll
    for (int o = 8; o >= 1; o >>= 1) s += __shfl_xor(s, o, 16);
    out[(size_t)r * 16 + l] = acc - m - logf(s);
}

// ---------------- launch ----------------

extern "C" void kernel_launch(void* const* d_in, const int* in_sizes, int n_in,
                              void* d_out, int out_size, void* d_ws, size_t ws_size,
                              hipStream_t stream) {
    const float* x = (const float*)d_in[0];
    const int* ei = (const int*)d_in[1];
    const float* W1 = (const float*)d_in[2];
    const float* b1 = (const float*)d_in[3];
    const float* W2 = (const float*)d_in[4];
    const float* b2 = (const float*)d_in[5];
    const float* W3 = (const float*)d_in[6];
    const float* b3 = (const float*)d_in[7];
    int N = in_sizes[0] / D_IN;
    int E = in_sizes[1] / 2;

    char* p = (char*)d_ws;
    auto alloc = [&](size_t bytes) -> void* {
        void* q = (void*)p;
        p += (bytes + 255) & ~(size_t)255;
        return q;
    };
    u32* cnt = (u32*)alloc((size_t)N * 4);
    u32* cursor = (u32*)alloc((size_t)N * 4);
    float* dinv = (float*)alloc((size_t)N * 4);
    u32* row_start = (u32*)alloc((size_t)(N + 1) * 4);
    u32* partial = (u32*)alloc(4096);
    u32* flag = (u32*)alloc(256);
    uint2* edata = (uint2*)alloc((size_t)E * 8);
    f16* wf1h = (f16*)alloc(16384 * 2);
    f16* wf1l = (f16*)alloc(16384 * 2);
    f16* wf2h = (f16*)alloc(16384 * 2);
    f16* wf2l = (f16*)alloc(16384 * 2);
    f16* wf3h = (f16*)alloc(2048 * 2);
    f16* wf3l = (f16*)alloc(2048 * 2);
    f16* h = (f16*)alloc((size_t)N * 128 * 2);
    f16* act = (f16*)alloc((size_t)N * 128 * 2);
    f16* h3 = (f16*)alloc((size_t)N * 16 * 2);
    (void)ws_size; (void)n_in; (void)out_size;

    hipMemsetAsync(cnt, 0, (size_t)N * 4, stream);
    hipMemsetAsync(cursor, 0, (size_t)N * 4, stream);
    hipMemsetAsync(flag, 0, 4, stream);

    int eb = (E + 255) / 256;
    int nb = (N + 255) / 256;  // 391 <= 512, scan2 single block handles it
    detect_k<<<32, 256, 0, stream>>>(ei, flag, 8192);
    count_rows<<<eb, 256, 0, stream>>>(ei, flag, cnt, E, N);
    dinv_k<<<nb, 256, 0, stream>>>(cnt, dinv, N);
    scan1<<<nb, 256, 0, stream>>>(cnt, row_start, partial, N);
    scan2<<<1, 512, 0, stream>>>(partial, nb);
    scan3<<<nb, 256, 0, stream>>>(row_start, partial, N, E);
    scatter_k<<<eb, 256, 0, stream>>>(ei, flag, dinv, row_start, cursor, edata, E, N);

    reformat_w<<<8, 256, 0, stream>>>(W1, wf1h, wf1l, 8);
    reformat_w<<<8, 256, 0, stream>>>(W2, wf2h, wf2l, 8);
    reformat_w<<<1, 256, 0, stream>>>(W3, wf3h, wf3l, 1);

    int gb = (N + 63) / 64;
    gemm128_l1<<<gb, 256, 0, stream>>>(x, wf1h, wf1l, h, N);
    agg128<<<(N + 3) / 4, 256, 0, stream>>>(h, edata, row_start, dinv, b1, act, N, 1);
    gemm128_l2<<<gb, 256, 0, stream>>>(act, wf2h, wf2l, h, N);
    agg128<<<(N + 3) / 4, 256, 0, stream>>>(h, edata, row_start, dinv, b2, act, N, 1);
    gemm16<<<gb, 256, 0, stream>>>(act, wf3h, wf3l, h3, N);
    agg16_lsm<<<(N + 15) / 16, 256, 0, stream>>>(h3, edata, row_start, dinv, b3,
                                                 (float*)d_out, N);
}